// Round 14
// baseline (164.932 us; speedup 1.0000x reference)
//
#include <hip/hip_runtime.h>
#include <math.h>

#define DIM 768
#define NHEADS 12
#define HD 64
#define BB 2
#define LL 2048
#define M_TOT (BB*LL)      /* 4096 */
#define NQKV (3*DIM)       /* 2304 */
#define QSCALE 0.18033688011112042f  /* 0.125 * log2(e) */

typedef __attribute__((ext_vector_type(8))) short short8;
typedef __attribute__((ext_vector_type(4))) float floatx4;

__device__ __forceinline__ unsigned short f2bf(float f) {
  unsigned int u = __float_as_uint(f);
  u += 0x7fff + ((u >> 16) & 1);   // round-to-nearest-even
  return (unsigned short)(u >> 16);
}

#if __has_builtin(__builtin_amdgcn_cvt_pk_bf16_f32)
typedef __attribute__((ext_vector_type(2))) __bf16 bf16x2_t;
__device__ __forceinline__ unsigned int pack2bf(float a, float b) {
  bf16x2_t r = __builtin_amdgcn_cvt_pk_bf16_f32(a, b);   // lo=a, hi=b, RNE
  return *(unsigned int*)&r;
}
#else
__device__ __forceinline__ unsigned int pack2bf(float a, float b) {
  unsigned int ua = __float_as_uint(a) + 0x8000u;
  unsigned int ub = __float_as_uint(b) + 0x8000u;
  return (ub & 0xffff0000u) | (ua >> 16);
}
#endif

#if __has_builtin(__builtin_amdgcn_exp2f)
#define EXP2(x) __builtin_amdgcn_exp2f(x)
#else
#define EXP2(x) exp2f(x)
#endif

// async global->LDS DMA, 16B/lane; LDS dst = wave-uniform base + lane*16
__device__ __forceinline__ void load_lds16(const unsigned short* g, unsigned short* l) {
  __builtin_amdgcn_global_load_lds(
      (const __attribute__((address_space(1))) unsigned int*)g,
      (__attribute__((address_space(3))) unsigned int*)l, 16, 0, 0);
}

// ============================================================================
// SWIZZLE INVARIANT (rule 21: both-sides-or-neither).
// LDS tiles are linear [rows][64 bf16]. S(el) = el ^ (((el>>6)&7)<<3) is
// pre-applied to global buffers (xb, wqkv_t, wproj_t, ab2 store
// buf[row][j] = orig[row][j ^ ((row&7)<<3)]), so linear global_load_lds yields
// LDS[y] = orig(S(y)); fragment reads at S(e) return orig(e). m0/n0 are
// multiples of 64, so (m0+row)&7 == row&7 — periodicity preserved.
// ============================================================================

// ---- prep: transpose-cast BOTH weights + cast x, all pre-swizzled ----
__global__ void prep_kernel(const float* __restrict__ x,
                            const float* __restrict__ Wqkv, const float* __restrict__ Wproj,
                            unsigned short* __restrict__ xb,
                            unsigned short* __restrict__ wqkv_t,
                            unsigned short* __restrict__ wproj_t) {
  __shared__ float tl[32][33];
  int bx = blockIdx.x;
  int t = threadIdx.x;
  if (bx >= 2304) {
    int idx = (bx - 2304) * 256 + t;     // 8-element chunk id, [0, 4096*96)
    int gr = idx / 96;
    int jc = (idx % 96) * 8;
    int xr = (gr & 7) << 3;
    const float* s = &x[(size_t)gr * 768 + (jc ^ xr)];
    float4 v0 = *(const float4*)s, v1 = *(const float4*)(s + 4);
    uint4 pk;
    pk.x = pack2bf(v0.x, v0.y); pk.y = pack2bf(v0.z, v0.w);
    pk.z = pack2bf(v1.x, v1.y); pk.w = pack2bf(v1.z, v1.w);
    *(uint4*)&xb[(size_t)gr * 768 + jc] = pk;
    return;
  }
  const float* src; unsigned short* dst; int C, r0, c0;
  if (bx < 1728) { src = Wqkv;  dst = wqkv_t;  C = NQKV; c0 = (bx % 72) * 32; r0 = (bx / 72) * 32; }
  else { int b2 = bx - 1728; src = Wproj; dst = wproj_t; C = DIM; c0 = (b2 % 24) * 32; r0 = (b2 / 24) * 32; }
  int tr = t >> 3, tc = (t & 7) * 4;
  float4 v = *(const float4*)&src[(size_t)(r0 + tr) * C + c0 + tc];
  tl[tr][tc] = v.x; tl[tr][tc + 1] = v.y; tl[tr][tc + 2] = v.z; tl[tr][tc + 3] = v.w;
  __syncthreads();
  int oc = t >> 3, orr = (t & 7) * 4;
  ushort4 o;
  o.x = f2bf(tl[orr][oc]); o.y = f2bf(tl[orr + 1][oc]);
  o.z = f2bf(tl[orr + 2][oc]); o.w = f2bf(tl[orr + 3][oc]);
  int R = c0 + oc;
  *(ushort4*)&dst[(size_t)R * 768 + ((r0 + orr) ^ ((R & 7) << 3))] = o;
}

// ---- 64xBN-tile bf16 MFMA GEMM, K=768, 2-PHASE PREFETCH (R13-verified) ----
template<int MODE>
__global__ __launch_bounds__(256) void gemm128_kernel(
    const unsigned short* __restrict__ Ab, const unsigned short* __restrict__ Bt,
    const float* __restrict__ bias, float* __restrict__ outf,
    unsigned short* __restrict__ qb, unsigned short* __restrict__ kb,
    unsigned short* __restrict__ vtb) {
  constexpr int BN = (MODE == 0) ? 128 : 64;   // n-tile
  constexpr int NF = BN / 32;                  // n-fragments per wave (4 or 2)
  __shared__ unsigned short sA[2][64 * 64];
  __shared__ unsigned short sB[2][BN * 64];
  int t = threadIdx.x;
  int bx = blockIdx.x;
  int m0 = (((bx & 7) << 3) | ((bx >> 3) & 7)) * 64;
  int n0 = (bx >> 6) * BN;
  int wave = t >> 6, lane = t & 63, ln = lane & 15, quad = lane >> 4;
  int wm = (wave >> 1) * 32, wn = (wave & 1) * (BN / 2);
  int xrl = (ln & 7) << 3;               // read-side swizzle (row&7 == ln&7)

  auto stage = [&](int buf, int kt) {
#pragma unroll
    for (int p = 0; p < NF; ++p) {
      int u = t + p * 256;
      int row = u >> 3, c = (u & 7) * 8;
      load_lds16(&Bt[(size_t)(n0 + row) * 768 + kt * 64 + c], &sB[buf][u * 8]);
    }
#pragma unroll
    for (int p = 0; p < 2; ++p) {
      int u = t + p * 256;
      int row = u >> 3, c = (u & 7) * 8;
      load_lds16(&Ab[(size_t)(m0 + row) * 768 + kt * 64 + c], &sA[buf][u * 8]);
    }
  };

  floatx4 acc[2][NF] = {};
  stage(0, 0);
  int cur = 0;
  for (int kt = 0; kt < 12; ++kt) {
    __syncthreads();
    if (kt + 1 < 12) stage(cur ^ 1, kt + 1);
    const unsigned short* cA = sA[cur];
    const unsigned short* cB = sB[cur];
    __builtin_amdgcn_s_setprio(1);
#pragma unroll
    for (int ks = 0; ks < 2; ++ks) {
      short8 af[2], bfr[NF];
      int co = (ks * 32 + quad * 8) ^ xrl;
#pragma unroll
      for (int s = 0; s < 2; ++s)
        af[s]  = *(const short8*)&cA[(wm + s * 16 + ln) * 64 + co];
#pragma unroll
      for (int s = 0; s < NF; ++s)
        bfr[s] = *(const short8*)&cB[(wn + s * 16 + ln) * 64 + co];
#pragma unroll
      for (int i = 0; i < 2; ++i)
#pragma unroll
        for (int j = 0; j < NF; ++j)
          acc[i][j] = __builtin_amdgcn_mfma_f32_16x16x32_bf16(af[i], bfr[j], acc[i][j], 0, 0, 0);
    }
    __builtin_amdgcn_s_setprio(0);
    cur ^= 1;
  }
#pragma unroll
  for (int mt = 0; mt < 2; ++mt)
#pragma unroll
    for (int nt = 0; nt < NF; ++nt)
#pragma unroll
      for (int r = 0; r < 4; ++r) {
        int row = m0 + wm + mt * 16 + quad * 4 + r;   // C/D: col=lane&15, row=quad*4+reg
        int col = n0 + wn + nt * 16 + ln;
        if (MODE == 0) {
          float val = acc[mt][nt][r] + bias[col];
          int which = (col >= 1536) ? 2 : (col >= 768) ? 1 : 0;
          int rem = col - which * 768;
          int h = rem >> 6, d = rem & 63;
          int b = row >> 11, i = row & 2047;
          int bh = b * NHEADS + h;
          if (which == 0) qb[((size_t)bh * LL + i) * HD + d] = f2bf(val * QSCALE);
          else if (which == 1) kb[((size_t)bh * LL + i) * HD + d] = f2bf(val);
          else vtb[((size_t)bh * HD + d) * LL + i] = f2bf(val);   // transposed V
        } else {
          outf[(size_t)row * 768 + col] = acc[mt][nt][r] + bias[col];
        }
      }
}

// ---- combine: ab2[gr][j] = bf16((opart0+opart1)*inv), pre-swizzled for DMA ----
__global__ void combine_kernel(const float* __restrict__ opart,
                               const float* __restrict__ lpart,
                               unsigned short* __restrict__ ab2) {
  int idx = blockIdx.x * 256 + threadIdx.x;
  int gr = idx / 96;
  int j0 = (idx % 96) * 8;
  int xr = (gr & 7) << 3;
  int jsrc = j0 ^ xr;                      // aligned 8-block: (j0+i)^xr = jsrc+i
  int bb = gr >> 11, ii = gr & 2047, h = jsrc >> 6;
  int bh = bb * NHEADS + h;
  float inv = 1.0f / (lpart[(size_t)bh * LL + ii] +
                      lpart[(size_t)(BB * NHEADS + bh) * LL + ii]);
  const float* s0 = &opart[(size_t)gr * 768 + jsrc];
  const float* s1 = s0 + (size_t)M_TOT * DIM;
  float4 a0 = *(const float4*)s0, a1 = *(const float4*)(s0 + 4);
  float4 b0 = *(const float4*)s1, b1 = *(const float4*)(s1 + 4);
  uint4 pk;
  pk.x = pack2bf((a0.x + b0.x) * inv, (a0.y + b0.y) * inv);
  pk.y = pack2bf((a0.z + b0.z) * inv, (a0.w + b0.w) * inv);
  pk.z = pack2bf((a1.x + b1.x) * inv, (a1.y + b1.y) * inv);
  pk.w = pack2bf((a1.z + b1.z) * inv, (a1.w + b1.w) * inv);
  *(uint4*)&ab2[(size_t)gr * 768 + j0] = pk;
}

// ---------------- flash v16: sP removed — in-register P via __shfl -----------
// Identical to R13's v15 except the P round-trip through LDS is replaced by
// register shuffles. Map INVERTED FROM THE WORKING sP write/read pair (not
// hand-derived): reader lane (ln,quad), chunk ks, element j gets
//   st[jm = 2ks + (quad>>1)][si][r = j&3]
//   from source lane  ln + 16*((quad&1)*2 + (j>>2)).
// Packed words W[jm][0]=pack(r0,r1), W[jm][1]=pack(r2,r3); target short8 =
// { shfl(W[jmq][0], s0), shfl(W[jmq][1], s0), shfl(W[jmq][0], s0+16),
//   shfl(W[jmq][1], s0+16) },  s0 = ln + 32*(quad&1),  jmq selected by
// quad>>1 (shfl-both-then-cndmask; selection must be by TARGET quad).
// exp values, l[si] accumulation order, and PV MFMA order are bit-identical
// to v15. LDS 40KB -> 32KB. __shfl is ds_bpermute (no new-instruction risk).
__global__ __launch_bounds__(256, 3) void flash16_kernel(
    const unsigned short* __restrict__ q, const unsigned short* __restrict__ k,
    const unsigned short* __restrict__ vt, float* __restrict__ opart,
    float* __restrict__ lpart) {
  __shared__ unsigned short sK[2][8 * 512];
  __shared__ unsigned short sV[2][8 * 512];
  int t = threadIdx.x;
  int wave = t >> 6, lane = t & 63, ln = lane & 15, quad = lane >> 4;
  int bx = blockIdx.x;
  int xcd = bx & 7, kk = bx >> 3;
  int bhjs = xcd * 6 + (kk % 6);
  int i0 = (kk / 6) * 128;
  int bh = bhjs >> 1, js = bhjs & 1;
  int b = bh / NHEADS, h = bh % NHEADS;
  const unsigned short* qb = q + (size_t)bh * LL * HD;
  const unsigned short* kb = k + (size_t)bh * LL * HD;
  const unsigned short* vtb = vt + (size_t)bh * HD * LL;
  int iw0 = wave * 32;
  int src0 = ln + ((lane & 16) << 1);    // ln + 32*(quad&1)
  int src1 = src0 + 16;
  bool hiq = (quad >> 1) != 0;           // quad 2,3 -> jm = 2ks+1
  short8 qfrag[2][2];
#pragma unroll
  for (int si = 0; si < 2; ++si)
#pragma unroll
    for (int ks = 0; ks < 2; ++ks)
      qfrag[si][ks] = *(const short8*)&qb[(size_t)(i0 + iw0 + si * 16 + ln) * HD + ks * 32 + quad * 8];
  float l[2] = {0.f, 0.f};
  floatx4 oacc[2][4] = {};
  {
    int j0 = js * 1024;
#pragma unroll
    for (int p = 0; p < 2; ++p) {
      int ck = wave * 2 + p;
      int jm = ck >> 1, ks = ck & 1;
      load_lds16(&kb[(size_t)(j0 + jm * 16 + ln) * HD + ks * 32 + quad * 8], &sK[0][ck * 512]);
      load_lds16(&vtb[(size_t)(jm * 16 + ln) * LL + j0 + ks * 32 + quad * 8], &sV[0][ck * 512]);
    }
  }
  for (int jt = 0; jt < 16; ++jt) {
    int cur = jt & 1;
    __syncthreads();   // drains buf[cur] DMA; fences buf[cur^1] readers
    if (jt + 1 < 16) {
      int j0n = js * 1024 + (jt + 1) * 64;
#pragma unroll
      for (int p = 0; p < 2; ++p) {
        int ck = wave * 2 + p;
        int jm = ck >> 1, ks = ck & 1;
        load_lds16(&kb[(size_t)(j0n + jm * 16 + ln) * HD + ks * 32 + quad * 8],
                   &sK[cur ^ 1][ck * 512]);
        load_lds16(&vtb[(size_t)(jm * 16 + ln) * LL + j0n + ks * 32 + quad * 8],
                   &sV[cur ^ 1][ck * 512]);
      }
    }
    const unsigned short* sKc = sK[cur];
    const unsigned short* sVc = sV[cur];
    floatx4 st[4][2] = {};
    __builtin_amdgcn_s_setprio(1);
#pragma unroll
    for (int ks = 0; ks < 2; ++ks)
#pragma unroll
      for (int jm = 0; jm < 4; ++jm) {
        short8 ak = *(const short8*)&sKc[(jm * 2 + ks) * 512 + lane * 8];
        st[jm][0] = __builtin_amdgcn_mfma_f32_16x16x32_bf16(ak, qfrag[0][ks], st[jm][0], 0, 0, 0);
        st[jm][1] = __builtin_amdgcn_mfma_f32_16x16x32_bf16(ak, qfrag[1][ks], st[jm][1], 0, 0, 0);
      }
    __builtin_amdgcn_s_setprio(0);
    // kp = key-half: exp+pack (same values/order as v15), shfl-transpose, PV
#pragma unroll
    for (int kp = 0; kp < 2; ++kp) {
      short8 bvk[4];
#pragma unroll
      for (int nt = 0; nt < 4; ++nt)
        bvk[nt] = *(const short8*)&sVc[(nt * 2 + kp) * 512 + lane * 8];
      short8 ap[2];
#pragma unroll
      for (int si = 0; si < 2; ++si) {
        unsigned int W0[2], W1[2];       // [jmi]: packed (r0,r1), (r2,r3)
#pragma unroll
        for (int jmi = 0; jmi < 2; ++jmi) {
          int jm = kp * 2 + jmi;
          float e0 = EXP2(st[jm][si][0]);
          float e1 = EXP2(st[jm][si][1]);
          float e2 = EXP2(st[jm][si][2]);
          float e3 = EXP2(st[jm][si][3]);
          l[si] += (e0 + e1) + (e2 + e3);
          W0[jmi] = pack2bf(e0, e1);
          W1[jmi] = pack2bf(e2, e3);
        }
        unsigned int a00 = (unsigned int)__shfl((int)W0[0], src0, 64);
        unsigned int a10 = (unsigned int)__shfl((int)W1[0], src0, 64);
        unsigned int a01 = (unsigned int)__shfl((int)W0[0], src1, 64);
        unsigned int a11 = (unsigned int)__shfl((int)W1[0], src1, 64);
        unsigned int b00 = (unsigned int)__shfl((int)W0[1], src0, 64);
        unsigned int b10 = (unsigned int)__shfl((int)W1[1], src0, 64);
        unsigned int b01 = (unsigned int)__shfl((int)W0[1], src1, 64);
        unsigned int b11 = (unsigned int)__shfl((int)W1[1], src1, 64);
        uint4 apw;
        apw.x = hiq ? b00 : a00;
        apw.y = hiq ? b10 : a10;
        apw.z = hiq ? b01 : a01;
        apw.w = hiq ? b11 : a11;
        ap[si] = *(short8*)&apw;
      }
#pragma unroll
      for (int si = 0; si < 2; ++si) {
        __builtin_amdgcn_s_setprio(1);
#pragma unroll
        for (int nt = 0; nt < 4; ++nt)
          oacc[si][nt] = __builtin_amdgcn_mfma_f32_16x16x32_bf16(ap[si], bvk[nt], oacc[si][nt], 0, 0, 0);
        __builtin_amdgcn_s_setprio(0);
      }
    }
  }
#pragma unroll
  for (int si = 0; si < 2; ++si) {
    l[si] += __shfl_xor(l[si], 16, 64);
    l[si] += __shfl_xor(l[si], 32, 64);
  }
  float* op = opart + (size_t)js * M_TOT * DIM;
  if (quad == 0) {
#pragma unroll
    for (int si = 0; si < 2; ++si)
      lpart[((size_t)js * BB * NHEADS + bh) * LL + i0 + iw0 + si * 16 + ln] = l[si];
  }
#pragma unroll
  for (int si = 0; si < 2; ++si)
#pragma unroll
    for (int r = 0; r < 4; ++r) {
      int row = i0 + iw0 + si * 16 + quad * 4 + r;
#pragma unroll
      for (int nt = 0; nt < 4; ++nt) {
        int d = nt * 16 + ln;
        op[((size_t)(b * LL + row)) * DIM + h * HD + d] = oacc[si][nt][r];
      }
    }
}

extern "C" void kernel_launch(void* const* d_in, const int* in_sizes, int n_in,
                              void* d_out, int out_size, void* d_ws, size_t ws_size,
                              hipStream_t stream) {
  (void)in_sizes; (void)n_in; (void)out_size; (void)ws_size;
  const float* x = (const float*)d_in[0];
  const float* Wqkv = (const float*)d_in[1];
  const float* bqkv = (const float*)d_in[2];
  const float* Wproj = (const float*)d_in[3];
  const float* bproj = (const float*)d_in[4];
  float* out = (float*)d_out;

  char* ws = (char*)d_ws;
  size_t off = 0;
  unsigned short* wqkv_t  = (unsigned short*)(ws + off); off += (size_t)NQKV * DIM * 2;
  unsigned short* wproj_t = (unsigned short*)(ws + off); off += (size_t)DIM * DIM * 2;
  unsigned short* xb      = (unsigned short*)(ws + off); off += (size_t)M_TOT * DIM * 2;
  unsigned short* qbuf    = (unsigned short*)(ws + off); off += (size_t)BB * NHEADS * LL * HD * 2;
  unsigned short* kbuf    = (unsigned short*)(ws + off); off += (size_t)BB * NHEADS * LL * HD * 2;
  unsigned short* vtbuf   = (unsigned short*)(ws + off); off += (size_t)BB * NHEADS * LL * HD * 2;
  float*          opart   = (float*)(ws + off);          off += (size_t)2 * M_TOT * DIM * 4;
  float*          lpart   = (float*)(ws + off);          off += (size_t)2 * BB * NHEADS * LL * 4;
  unsigned short* ab2     = xb;   // xb is dead after gemm<0>; reuse (same size)

  prep_kernel<<<dim3(2304 + 1536), 256, 0, stream>>>(x, Wqkv, Wproj, xb, wqkv_t, wproj_t);
  gemm128_kernel<0><<<dim3(64 * (NQKV / 128)), 256, 0, stream>>>(
      xb, wqkv_t, bqkv, nullptr, qbuf, kbuf, vtbuf);
  flash16_kernel<<<dim3((LL / 128) * 24 * 2), 256, 0, stream>>>(qbuf, kbuf, vtbuf, opart, lpart);
  combine_kernel<<<dim3((M_TOT * 96) / 256), 256, 0, stream>>>(opart, lpart, ab2);
  gemm128_kernel<1><<<dim3(64 * (DIM / 64)), 256, 0, stream>>>(
      ab2, wproj_t, bproj, out, nullptr, nullptr, nullptr);
}

// Round 15
// 163.390 us; speedup vs baseline: 1.0094x; 1.0094x over previous
//
#include <hip/hip_runtime.h>
#include <math.h>

#define DIM 768
#define NHEADS 12
#define HD 64
#define BB 2
#define LL 2048
#define M_TOT (BB*LL)      /* 4096 */
#define NQKV (3*DIM)       /* 2304 */
#define QSCALE 0.18033688011112042f  /* 0.125 * log2(e) */

typedef __attribute__((ext_vector_type(8))) short short8;
typedef __attribute__((ext_vector_type(4))) float floatx4;

__device__ __forceinline__ unsigned short f2bf(float f) {
  unsigned int u = __float_as_uint(f);
  u += 0x7fff + ((u >> 16) & 1);   // round-to-nearest-even
  return (unsigned short)(u >> 16);
}

#if __has_builtin(__builtin_amdgcn_cvt_pk_bf16_f32)
typedef __attribute__((ext_vector_type(2))) __bf16 bf16x2_t;
__device__ __forceinline__ unsigned int pack2bf(float a, float b) {
  bf16x2_t r = __builtin_amdgcn_cvt_pk_bf16_f32(a, b);   // lo=a, hi=b, RNE
  return *(unsigned int*)&r;
}
#else
__device__ __forceinline__ unsigned int pack2bf(float a, float b) {
  unsigned int ua = __float_as_uint(a) + 0x8000u;
  unsigned int ub = __float_as_uint(b) + 0x8000u;
  return (ub & 0xffff0000u) | (ua >> 16);
}
#endif

#if __has_builtin(__builtin_amdgcn_exp2f)
#define EXP2(x) __builtin_amdgcn_exp2f(x)
#else
#define EXP2(x) exp2f(x)
#endif

// async global->LDS DMA, 16B/lane; LDS dst = wave-uniform base + lane*16
__device__ __forceinline__ void load_lds16(const unsigned short* g, unsigned short* l) {
  __builtin_amdgcn_global_load_lds(
      (const __attribute__((address_space(1))) unsigned int*)g,
      (__attribute__((address_space(3))) unsigned int*)l, 16, 0, 0);
}

// ============================================================================
// SWIZZLE INVARIANT (rule 21: both-sides-or-neither).
// LDS tiles are linear [rows][64 bf16]. S(el) = el ^ (((el>>6)&7)<<3) is
// pre-applied to global buffers (xb, wqkv_t, wproj_t, ab2 store
// buf[row][j] = orig[row][j ^ ((row&7)<<3)]), so linear global_load_lds yields
// LDS[y] = orig(S(y)); fragment reads at S(e) return orig(e). m0/n0 are
// multiples of 64, so (m0+row)&7 == row&7 — periodicity preserved.
// ============================================================================

// ---- prep: transpose-cast BOTH weights + cast x, all pre-swizzled ----
__global__ void prep_kernel(const float* __restrict__ x,
                            const float* __restrict__ Wqkv, const float* __restrict__ Wproj,
                            unsigned short* __restrict__ xb,
                            unsigned short* __restrict__ wqkv_t,
                            unsigned short* __restrict__ wproj_t) {
  __shared__ float tl[32][33];
  int bx = blockIdx.x;
  int t = threadIdx.x;
  if (bx >= 2304) {
    int idx = (bx - 2304) * 256 + t;     // 8-element chunk id, [0, 4096*96)
    int gr = idx / 96;
    int jc = (idx % 96) * 8;
    int xr = (gr & 7) << 3;
    const float* s = &x[(size_t)gr * 768 + (jc ^ xr)];
    float4 v0 = *(const float4*)s, v1 = *(const float4*)(s + 4);
    uint4 pk;
    pk.x = pack2bf(v0.x, v0.y); pk.y = pack2bf(v0.z, v0.w);
    pk.z = pack2bf(v1.x, v1.y); pk.w = pack2bf(v1.z, v1.w);
    *(uint4*)&xb[(size_t)gr * 768 + jc] = pk;
    return;
  }
  const float* src; unsigned short* dst; int C, r0, c0;
  if (bx < 1728) { src = Wqkv;  dst = wqkv_t;  C = NQKV; c0 = (bx % 72) * 32; r0 = (bx / 72) * 32; }
  else { int b2 = bx - 1728; src = Wproj; dst = wproj_t; C = DIM; c0 = (b2 % 24) * 32; r0 = (b2 / 24) * 32; }
  int tr = t >> 3, tc = (t & 7) * 4;
  float4 v = *(const float4*)&src[(size_t)(r0 + tr) * C + c0 + tc];
  tl[tr][tc] = v.x; tl[tr][tc + 1] = v.y; tl[tr][tc + 2] = v.z; tl[tr][tc + 3] = v.w;
  __syncthreads();
  int oc = t >> 3, orr = (t & 7) * 4;
  ushort4 o;
  o.x = f2bf(tl[orr][oc]); o.y = f2bf(tl[orr + 1][oc]);
  o.z = f2bf(tl[orr + 2][oc]); o.w = f2bf(tl[orr + 3][oc]);
  int R = c0 + oc;
  *(ushort4*)&dst[(size_t)R * 768 + ((r0 + orr) ^ ((R & 7) << 3))] = o;
}

// ---- 64xBN-tile bf16 MFMA GEMM, K=768, 2-PHASE PREFETCH (R13-verified) ----
// MODE 0: BN=128, grid 1152; A=xb, B=wqkv_t; scatters q (pre-scaled), k, V^T.
// MODE 1: BN=64, grid 768 = 3 blk/CU; A=ab2, B=wproj_t; out = acc + bias.
// XCD-chunked m-map (R11, bijective): m0=((bx&7)*8+((bx>>3)&7))*64.
template<int MODE>
__global__ __launch_bounds__(256) void gemm128_kernel(
    const unsigned short* __restrict__ Ab, const unsigned short* __restrict__ Bt,
    const float* __restrict__ bias, float* __restrict__ outf,
    unsigned short* __restrict__ qb, unsigned short* __restrict__ kb,
    unsigned short* __restrict__ vtb) {
  constexpr int BN = (MODE == 0) ? 128 : 64;   // n-tile
  constexpr int NF = BN / 32;                  // n-fragments per wave (4 or 2)
  __shared__ unsigned short sA[2][64 * 64];
  __shared__ unsigned short sB[2][BN * 64];
  int t = threadIdx.x;
  int bx = blockIdx.x;
  int m0 = (((bx & 7) << 3) | ((bx >> 3) & 7)) * 64;
  int n0 = (bx >> 6) * BN;
  int wave = t >> 6, lane = t & 63, ln = lane & 15, quad = lane >> 4;
  int wm = (wave >> 1) * 32, wn = (wave & 1) * (BN / 2);
  int xrl = (ln & 7) << 3;               // read-side swizzle (row&7 == ln&7)

  auto stage = [&](int buf, int kt) {
#pragma unroll
    for (int p = 0; p < NF; ++p) {
      int u = t + p * 256;
      int row = u >> 3, c = (u & 7) * 8;
      load_lds16(&Bt[(size_t)(n0 + row) * 768 + kt * 64 + c], &sB[buf][u * 8]);
    }
#pragma unroll
    for (int p = 0; p < 2; ++p) {
      int u = t + p * 256;
      int row = u >> 3, c = (u & 7) * 8;
      load_lds16(&Ab[(size_t)(m0 + row) * 768 + kt * 64 + c], &sA[buf][u * 8]);
    }
  };

  floatx4 acc[2][NF] = {};
  stage(0, 0);
  int cur = 0;
  for (int kt = 0; kt < 12; ++kt) {
    __syncthreads();
    if (kt + 1 < 12) stage(cur ^ 1, kt + 1);
    const unsigned short* cA = sA[cur];
    const unsigned short* cB = sB[cur];
    __builtin_amdgcn_s_setprio(1);
#pragma unroll
    for (int ks = 0; ks < 2; ++ks) {
      short8 af[2], bfr[NF];
      int co = (ks * 32 + quad * 8) ^ xrl;
#pragma unroll
      for (int s = 0; s < 2; ++s)
        af[s]  = *(const short8*)&cA[(wm + s * 16 + ln) * 64 + co];
#pragma unroll
      for (int s = 0; s < NF; ++s)
        bfr[s] = *(const short8*)&cB[(wn + s * 16 + ln) * 64 + co];
#pragma unroll
      for (int i = 0; i < 2; ++i)
#pragma unroll
        for (int j = 0; j < NF; ++j)
          acc[i][j] = __builtin_amdgcn_mfma_f32_16x16x32_bf16(af[i], bfr[j], acc[i][j], 0, 0, 0);
    }
    __builtin_amdgcn_s_setprio(0);
    cur ^= 1;
  }
#pragma unroll
  for (int mt = 0; mt < 2; ++mt)
#pragma unroll
    for (int nt = 0; nt < NF; ++nt)
#pragma unroll
      for (int r = 0; r < 4; ++r) {
        int row = m0 + wm + mt * 16 + quad * 4 + r;   // C/D: col=lane&15, row=quad*4+reg
        int col = n0 + wn + nt * 16 + ln;
        if (MODE == 0) {
          float val = acc[mt][nt][r] + bias[col];
          int which = (col >= 1536) ? 2 : (col >= 768) ? 1 : 0;
          int rem = col - which * 768;
          int h = rem >> 6, d = rem & 63;
          int b = row >> 11, i = row & 2047;
          int bh = b * NHEADS + h;
          if (which == 0) qb[((size_t)bh * LL + i) * HD + d] = f2bf(val * QSCALE);
          else if (which == 1) kb[((size_t)bh * LL + i) * HD + d] = f2bf(val);
          else vtb[((size_t)bh * HD + d) * LL + i] = f2bf(val);   // transposed V
        } else {
          outf[(size_t)row * 768 + col] = acc[mt][nt][r] + bias[col];
        }
      }
}

// ---- combine: ab2[gr][j] = bf16((opart0+opart1)*inv), pre-swizzled for DMA ----
__global__ void combine_kernel(const float* __restrict__ opart,
                               const float* __restrict__ lpart,
                               unsigned short* __restrict__ ab2) {
  int idx = blockIdx.x * 256 + threadIdx.x;
  int gr = idx / 96;
  int j0 = (idx % 96) * 8;
  int xr = (gr & 7) << 3;
  int jsrc = j0 ^ xr;                      // aligned 8-block: (j0+i)^xr = jsrc+i
  int bb = gr >> 11, ii = gr & 2047, h = jsrc >> 6;
  int bh = bb * NHEADS + h;
  float inv = 1.0f / (lpart[(size_t)bh * LL + ii] +
                      lpart[(size_t)(BB * NHEADS + bh) * LL + ii]);
  const float* s0 = &opart[(size_t)gr * 768 + jsrc];
  const float* s1 = s0 + (size_t)M_TOT * DIM;
  float4 a0 = *(const float4*)s0, a1 = *(const float4*)(s0 + 4);
  float4 b0 = *(const float4*)s1, b1 = *(const float4*)(s1 + 4);
  uint4 pk;
  pk.x = pack2bf((a0.x + b0.x) * inv, (a0.y + b0.y) * inv);
  pk.y = pack2bf((a0.z + b0.z) * inv, (a0.w + b0.w) * inv);
  pk.z = pack2bf((a1.x + b1.x) * inv, (a1.y + b1.y) * inv);
  pk.w = pack2bf((a1.z + b1.z) * inv, (a1.w + b1.w) * inv);
  *(uint4*)&ab2[(size_t)gr * 768 + j0] = pk;
}

// ---------------- flash v15 (R10/R13-verified): kp-outer PV, XCD-local KV ----
__global__ __launch_bounds__(256, 3) void flash15_kernel(
    const unsigned short* __restrict__ q, const unsigned short* __restrict__ k,
    const unsigned short* __restrict__ vt, float* __restrict__ opart,
    float* __restrict__ lpart) {
  __shared__ unsigned short sK[2][8 * 512];
  __shared__ unsigned short sV[2][8 * 512];
  __shared__ unsigned short sP[4][2 * 512];
  int t = threadIdx.x;
  int wave = t >> 6, lane = t & 63, ln = lane & 15, quad = lane >> 4;
  int bx = blockIdx.x;
  int xcd = bx & 7, kk = bx >> 3;
  int bhjs = xcd * 6 + (kk % 6);
  int i0 = (kk / 6) * 128;
  int bh = bhjs >> 1, js = bhjs & 1;
  int b = bh / NHEADS, h = bh % NHEADS;
  const unsigned short* qb = q + (size_t)bh * LL * HD;
  const unsigned short* kb = k + (size_t)bh * LL * HD;
  const unsigned short* vtb = vt + (size_t)bh * HD * LL;
  int iw0 = wave * 32;
  short8 qfrag[2][2];
#pragma unroll
  for (int si = 0; si < 2; ++si)
#pragma unroll
    for (int ks = 0; ks < 2; ++ks)
      qfrag[si][ks] = *(const short8*)&qb[(size_t)(i0 + iw0 + si * 16 + ln) * HD + ks * 32 + quad * 8];
  unsigned short* sPw = sP[wave];
  float l[2] = {0.f, 0.f};
  floatx4 oacc[2][4] = {};
  {
    int j0 = js * 1024;
#pragma unroll
    for (int p = 0; p < 2; ++p) {
      int ck = wave * 2 + p;
      int jm = ck >> 1, ks = ck & 1;
      load_lds16(&kb[(size_t)(j0 + jm * 16 + ln) * HD + ks * 32 + quad * 8], &sK[0][ck * 512]);
      load_lds16(&vtb[(size_t)(jm * 16 + ln) * LL + j0 + ks * 32 + quad * 8], &sV[0][ck * 512]);
    }
  }
  for (int jt = 0; jt < 16; ++jt) {
    int cur = jt & 1;
    __syncthreads();   // drains buf[cur] DMA; fences buf[cur^1] readers
    if (jt + 1 < 16) {
      int j0n = js * 1024 + (jt + 1) * 64;
#pragma unroll
      for (int p = 0; p < 2; ++p) {
        int ck = wave * 2 + p;
        int jm = ck >> 1, ks = ck & 1;
        load_lds16(&kb[(size_t)(j0n + jm * 16 + ln) * HD + ks * 32 + quad * 8],
                   &sK[cur ^ 1][ck * 512]);
        load_lds16(&vtb[(size_t)(jm * 16 + ln) * LL + j0n + ks * 32 + quad * 8],
                   &sV[cur ^ 1][ck * 512]);
      }
    }
    const unsigned short* sKc = sK[cur];
    const unsigned short* sVc = sV[cur];
    floatx4 st[4][2] = {};
    __builtin_amdgcn_s_setprio(1);
#pragma unroll
    for (int ks = 0; ks < 2; ++ks)
#pragma unroll
      for (int jm = 0; jm < 4; ++jm) {
        short8 ak = *(const short8*)&sKc[(jm * 2 + ks) * 512 + lane * 8];
        st[jm][0] = __builtin_amdgcn_mfma_f32_16x16x32_bf16(ak, qfrag[0][ks], st[jm][0], 0, 0, 0);
        st[jm][1] = __builtin_amdgcn_mfma_f32_16x16x32_bf16(ak, qfrag[1][ks], st[jm][1], 0, 0, 0);
      }
    __builtin_amdgcn_s_setprio(0);
    // kp = key-half: exp+pack+sP-write for jm{2kp,2kp+1}, then PV on that half
#pragma unroll
    for (int kp = 0; kp < 2; ++kp) {
      short8 bvk[4];
#pragma unroll
      for (int nt = 0; nt < 4; ++nt)
        bvk[nt] = *(const short8*)&sVc[(nt * 2 + kp) * 512 + lane * 8];
#pragma unroll
      for (int si = 0; si < 2; ++si)
#pragma unroll
        for (int jmi = 0; jmi < 2; ++jmi) {
          int jm = kp * 2 + jmi;
          float e0 = EXP2(st[jm][si][0]);
          float e1 = EXP2(st[jm][si][1]);
          float e2 = EXP2(st[jm][si][2]);
          float e3 = EXP2(st[jm][si][3]);
          l[si] += (e0 + e1) + (e2 + e3);
          uint2 pk;
          pk.x = pack2bf(e0, e1);
          pk.y = pack2bf(e2, e3);
          int elem = si * 512 +
                     (((jmi * 2 + (quad >> 1)) * 16 + ln) * 8) + (quad & 1) * 4;
          *(uint2*)&sPw[elem] = pk;
        }
#pragma unroll
      for (int si = 0; si < 2; ++si) {
        short8 ap = *(const short8*)&sPw[si * 512 + lane * 8];
        __builtin_amdgcn_s_setprio(1);
#pragma unroll
        for (int nt = 0; nt < 4; ++nt)
          oacc[si][nt] = __builtin_amdgcn_mfma_f32_16x16x32_bf16(ap, bvk[nt], oacc[si][nt], 0, 0, 0);
        __builtin_amdgcn_s_setprio(0);
      }
    }
  }
#pragma unroll
  for (int si = 0; si < 2; ++si) {
    l[si] += __shfl_xor(l[si], 16, 64);
    l[si] += __shfl_xor(l[si], 32, 64);
  }
  float* op = opart + (size_t)js * M_TOT * DIM;
  if (quad == 0) {
#pragma unroll
    for (int si = 0; si < 2; ++si)
      lpart[((size_t)js * BB * NHEADS + bh) * LL + i0 + iw0 + si * 16 + ln] = l[si];
  }
#pragma unroll
  for (int si = 0; si < 2; ++si)
#pragma unroll
    for (int r = 0; r < 4; ++r) {
      int row = i0 + iw0 + si * 16 + quad * 4 + r;
#pragma unroll
      for (int nt = 0; nt < 4; ++nt) {
        int d = nt * 16 + ln;
        op[((size_t)(b * LL + row)) * DIM + h * HD + d] = oacc[si][nt][r];
      }
    }
}

extern "C" void kernel_launch(void* const* d_in, const int* in_sizes, int n_in,
                              void* d_out, int out_size, void* d_ws, size_t ws_size,
                              hipStream_t stream) {
  (void)in_sizes; (void)n_in; (void)out_size; (void)ws_size;
  const float* x = (const float*)d_in[0];
  const float* Wqkv = (const float*)d_in[1];
  const float* bqkv = (const float*)d_in[2];
  const float* Wproj = (const float*)d_in[3];
  const float* bproj = (const float*)d_in[4];
  float* out = (float*)d_out;

  char* ws = (char*)d_ws;
  size_t off = 0;
  unsigned short* wqkv_t  = (unsigned short*)(ws + off); off += (size_t)NQKV * DIM * 2;
  unsigned short* wproj_t = (unsigned short*)(ws + off); off += (size_t)DIM * DIM * 2;
  unsigned short* xb      = (unsigned short*)(ws + off); off += (size_t)M_TOT * DIM * 2;
  unsigned short* qbuf    = (unsigned short*)(ws + off); off += (size_t)BB * NHEADS * LL * HD * 2;
  unsigned short* kbuf    = (unsigned short*)(ws + off); off += (size_t)BB * NHEADS * LL * HD * 2;
  unsigned short* vtbuf   = (unsigned short*)(ws + off); off += (size_t)BB * NHEADS * LL * HD * 2;
  float*          opart   = (float*)(ws + off);          off += (size_t)2 * M_TOT * DIM * 4;
  float*          lpart   = (float*)(ws + off);          off += (size_t)2 * BB * NHEADS * LL * 4;
  unsigned short* ab2     = xb;   // xb is dead after gemm<0>; reuse (same size)

  prep_kernel<<<dim3(2304 + 1536), 256, 0, stream>>>(x, Wqkv, Wproj, xb, wqkv_t, wproj_t);
  gemm128_kernel<0><<<dim3(64 * (NQKV / 128)), 256, 0, stream>>>(
      xb, wqkv_t, bqkv, nullptr, qbuf, kbuf, vtbuf);
  flash15_kernel<<<dim3((LL / 128) * 24 * 2), 256, 0, stream>>>(qbuf, kbuf, vtbuf, opart, lpart);
  combine_kernel<<<dim3((M_TOT * 96) / 256), 256, 0, stream>>>(opart, lpart, ab2);
  gemm128_kernel<1><<<dim3(64 * (DIM / 64)), 256, 0, stream>>>(
      ab2, wproj_t, bproj, out, nullptr, nullptr, nullptr);
}